// Round 1
// baseline (938.891 us; speedup 1.0000x reference)
//
#include <hip/hip_runtime.h>
#include <math.h>

#define N_NODES 50000
#define N_GRAPHS 64
#define HID 128

__device__ __forceinline__ float lrelu(float e) { return e > 0.f ? e : 0.2f * e; }

// ---------------- CSR build ----------------
__global__ void count_kernel(const int* __restrict__ dst, int n_e, int* __restrict__ counts) {
    int e = blockIdx.x * blockDim.x + threadIdx.x;
    if (e < n_e) atomicAdd(&counts[dst[e]], 1);
}

__global__ __launch_bounds__(1024) void scan_kernel(const int* __restrict__ counts,
                                                    int* __restrict__ offs,
                                                    int* __restrict__ cursor) {
    __shared__ int part[1024];
    const int CH = (N_NODES + 1023) / 1024;  // 49
    int t = threadIdx.x;
    int base = t * CH;
    int s = 0;
    for (int i = 0; i < CH; ++i) {
        int idx = base + i;
        if (idx < N_NODES) s += counts[idx];
    }
    part[t] = s;
    __syncthreads();
    for (int off = 1; off < 1024; off <<= 1) {
        int v = (t >= off) ? part[t - off] : 0;
        __syncthreads();
        part[t] += v;
        __syncthreads();
    }
    int run = (t == 0) ? 0 : part[t - 1];
    for (int i = 0; i < CH; ++i) {
        int idx = base + i;
        if (idx < N_NODES) {
            offs[idx] = run;
            cursor[idx] = run;
            run += counts[idx];
        }
    }
    if (t == 0) offs[N_NODES] = part[1023];
}

__global__ void scatter_kernel(const int* __restrict__ src, const int* __restrict__ dst, int n_e,
                               int* __restrict__ cursor, int* __restrict__ csr_src) {
    int e = blockIdx.x * blockDim.x + threadIdx.x;
    if (e >= n_e) return;
    int d = dst[e];
    int pos = atomicAdd(&cursor[d], 1);
    csr_src[pos] = src[e];
}

// ---------------- graph boundary detection (batch is sorted) ----------------
__global__ void init_start(int* __restrict__ start) {
    int i = threadIdx.x;
    if (i < N_GRAPHS + 1) start[i] = N_NODES;
}

__global__ void find_start(const int* __restrict__ batch, int* __restrict__ start) {
    int i = blockIdx.x * blockDim.x + threadIdx.x;
    if (i < N_NODES) atomicMin(&start[batch[i]], i);
}

__global__ void fix_start(int* __restrict__ start) {
    if (threadIdx.x == 0) {
        for (int g = N_GRAPHS - 1; g >= 0; --g)
            if (start[g] == N_NODES) start[g] = start[g + 1];
    }
}

// ---------------- fused GEMM + alpha: H = X@W, AS = H@a_src, AD = H@a_dst ----------------
// Block: 256 threads, 32 rows x 128 cols. W staged in two 64-row K-halves (32KB each).
// Thread (j = t&15, g = t>>4): rows 2g,2g+1 ; cols j+16u (u=0..7)  -> conflict-free LDS.
__global__ __launch_bounds__(256) void gemm_alpha(const float* __restrict__ X,
                                                  const float* __restrict__ W,
                                                  const float* __restrict__ av_s,
                                                  const float* __restrict__ av_d,
                                                  float* __restrict__ H,
                                                  float* __restrict__ AS,
                                                  float* __restrict__ AD) {
    __shared__ float sW[64 * 128];   // 32 KB (one K-half)
    __shared__ float sX[32][132];    // padded stride -> conflict-free row reads
    __shared__ float sAs[128], sAd[128];

    int t = threadIdx.x;
    if (t < 128) { sAs[t] = av_s[t]; sAd[t] = av_d[t]; }

    int row0 = blockIdx.x * 32;
    for (int i = t * 4; i < 32 * 128; i += 1024) {
        int r = i >> 7, c = i & 127;
        int gr = row0 + r;
        float4 v = make_float4(0.f, 0.f, 0.f, 0.f);
        if (gr < N_NODES) v = *(const float4*)(X + (size_t)gr * 128 + c);
        *(float4*)&sX[r][c] = v;
    }

    int j = t & 15, g = t >> 4;
    int r0 = g * 2;
    float acc0[8], acc1[8];
#pragma unroll
    for (int u = 0; u < 8; ++u) { acc0[u] = 0.f; acc1[u] = 0.f; }

    for (int half = 0; half < 2; ++half) {
        __syncthreads();  // protect sW reuse
        for (int i = t * 4; i < 64 * 128; i += 1024)
            *(float4*)&sW[i] = *(const float4*)(W + half * 64 * 128 + i);
        __syncthreads();
        int kbase = half * 64;
        for (int k = 0; k < 64; ++k) {
            float x0 = sX[r0][kbase + k];
            float x1 = sX[r0 + 1][kbase + k];
#pragma unroll
            for (int u = 0; u < 8; ++u) {
                float w = sW[k * 128 + j + 16 * u];
                acc0[u] = fmaf(x0, w, acc0[u]);
                acc1[u] = fmaf(x1, w, acc1[u]);
            }
        }
    }

    // epilogue: store H, fused alpha dot-products
    int gr0 = row0 + r0, gr1 = gr0 + 1;
    float as0 = 0.f, ad0 = 0.f, as1 = 0.f, ad1 = 0.f;
#pragma unroll
    for (int u = 0; u < 8; ++u) {
        int c = j + 16 * u;
        as0 += acc0[u] * sAs[c];
        ad0 += acc0[u] * sAd[c];
        as1 += acc1[u] * sAs[c];
        ad1 += acc1[u] * sAd[c];
        if (gr0 < N_NODES) H[(size_t)gr0 * 128 + c] = acc0[u];
        if (gr1 < N_NODES) H[(size_t)gr1 * 128 + c] = acc1[u];
    }
#pragma unroll
    for (int off = 1; off < 16; off <<= 1) {
        as0 += __shfl_xor(as0, off);
        ad0 += __shfl_xor(ad0, off);
        as1 += __shfl_xor(as1, off);
        ad1 += __shfl_xor(ad1, off);
    }
    if (j == 0) {
        if (gr0 < N_NODES) { AS[gr0] = as0; AD[gr0] = ad0; }
        if (gr1 < N_NODES) { AS[gr1] = as1; AD[gr1] = ad1; }
    }
}

// ---------------- attention + aggregation: one wave per dst node ----------------
__global__ __launch_bounds__(256) void aggregate_kernel(const float* __restrict__ H,
                                                        const float* __restrict__ AS,
                                                        const float* __restrict__ AD,
                                                        const int* __restrict__ offs,
                                                        const int* __restrict__ csr_src,
                                                        const float* __restrict__ bias,
                                                        float* __restrict__ OUT) {
    int node = blockIdx.x * 4 + (threadIdx.x >> 6);
    if (node >= N_NODES) return;
    int lane = threadIdx.x & 63;
    int beg = offs[node], end = offs[node + 1];
    float ad = AD[node];
    float eself = lrelu(AS[node] + ad);

    // phase 1: segment max (lanes strided over edges)
    float mym = -INFINITY;
    for (int i = beg + lane; i < end; i += 64) {
        int s = csr_src[i];
        mym = fmaxf(mym, lrelu(AS[s] + ad));
    }
#pragma unroll
    for (int off = 32; off; off >>= 1) mym = fmaxf(mym, __shfl_xor(mym, off));
    float m = fmaxf(mym, eself);

    // phase 2: sum of exp(e - m)
    float ssum = 0.f;
    for (int i = beg + lane; i < end; i += 64) {
        int s = csr_src[i];
        ssum += expf(lrelu(AS[s] + ad) - m);
    }
#pragma unroll
    for (int off = 32; off; off >>= 1) ssum += __shfl_xor(ssum, off);
    ssum += expf(eself - m);
    float inv = 1.f / (ssum + 1e-16f);

    // phase 3: weighted gather of h[src] rows; lane owns channels (lane, lane+64)
    float acc0 = 0.f, acc1 = 0.f;
    for (int i = beg; i < end; ++i) {
        int s = csr_src[i];
        float coef = expf(lrelu(AS[s] + ad) - m);
        acc0 = fmaf(coef, H[(size_t)s * 128 + lane], acc0);
        acc1 = fmaf(coef, H[(size_t)s * 128 + 64 + lane], acc1);
    }
    {
        float coef = expf(eself - m);
        acc0 = fmaf(coef, H[(size_t)node * 128 + lane], acc0);
        acc1 = fmaf(coef, H[(size_t)node * 128 + 64 + lane], acc1);
    }
    float o0 = acc0 * inv + bias[lane];
    float o1 = acc1 * inv + bias[lane + 64];
    o0 = o0 > 0.f ? o0 : expm1f(o0);   // elu
    o1 = o1 > 0.f ? o1 : expm1f(o1);
    OUT[(size_t)node * 128 + lane] = o0;
    OUT[(size_t)node * 128 + 64 + lane] = o1;
}

// ---------------- global mean pool ----------------
__global__ __launch_bounds__(512) void pool_kernel(const float* __restrict__ F,
                                                   const int* __restrict__ start,
                                                   float* __restrict__ out) {
    __shared__ float red[512];
    int g = blockIdx.x;
    int t = threadIdx.x;
    int c = t & 127, sub = t >> 7;  // 4 sub-chunks
    int b = start[g], e = start[g + 1];
    float acc = 0.f;
    for (int i = b + sub; i < e; i += 4) acc += F[(size_t)i * 128 + c];
    red[t] = acc;
    __syncthreads();
    if (sub == 0) {
        float v = red[c] + red[c + 128] + red[c + 256] + red[c + 384];
        int cnt = e - b;
        out[(size_t)g * 128 + c] = v / (float)(cnt > 1 ? cnt : 1);
    }
}

extern "C" void kernel_launch(void* const* d_in, const int* in_sizes, int n_in,
                              void* d_out, int out_size, void* d_ws, size_t ws_size,
                              hipStream_t stream) {
    const float* x = (const float*)d_in[0];
    const int* edge_index = (const int*)d_in[1];
    const int* batch = (const int*)d_in[2];
    const float* W[3]   = {(const float*)d_in[3], (const float*)d_in[7], (const float*)d_in[11]};
    const float* avs[3] = {(const float*)d_in[4], (const float*)d_in[8], (const float*)d_in[12]};
    const float* avd[3] = {(const float*)d_in[5], (const float*)d_in[9], (const float*)d_in[13]};
    const float* bb[3]  = {(const float*)d_in[6], (const float*)d_in[10], (const float*)d_in[14]};
    int E0 = in_sizes[1] / 2;
    const int* esrc = edge_index;
    const int* edst = edge_index + E0;

    // workspace bump allocator (256B aligned)
    char* p = (char*)d_ws;
    auto alloc = [&](size_t bytes) -> void* {
        void* q = (void*)p;
        p += (bytes + 255) & ~(size_t)255;
        return q;
    };
    int* counts   = (int*)alloc((size_t)N_NODES * 4);
    int* offs     = (int*)alloc((size_t)(N_NODES + 1) * 4);
    int* cursor   = (int*)alloc((size_t)N_NODES * 4);
    int* csr_src  = (int*)alloc((size_t)E0 * 4);
    int* start    = (int*)alloc((N_GRAPHS + 1) * 4);
    float* AS     = (float*)alloc((size_t)N_NODES * 4);
    float* AD     = (float*)alloc((size_t)N_NODES * 4);
    float* Hbuf   = (float*)alloc((size_t)N_NODES * HID * 4);
    float* FA     = (float*)alloc((size_t)N_NODES * HID * 4);
    float* FB     = (float*)alloc((size_t)N_NODES * HID * 4);

    // CSR build (per call; ws is re-poisoned each replay)
    hipMemsetAsync(counts, 0, (size_t)N_NODES * 4, stream);
    count_kernel<<<(E0 + 255) / 256, 256, 0, stream>>>(edst, E0, counts);
    scan_kernel<<<1, 1024, 0, stream>>>(counts, offs, cursor);
    scatter_kernel<<<(E0 + 255) / 256, 256, 0, stream>>>(esrc, edst, E0, cursor, csr_src);

    // graph boundaries
    init_start<<<1, 128, 0, stream>>>(start);
    find_start<<<(N_NODES + 255) / 256, 256, 0, stream>>>(batch, start);
    fix_start<<<1, 64, 0, stream>>>(start);

    // 3 GAT layers
    const float* cur = x;
    float* feat[2] = {FA, FB};
    for (int l = 0; l < 3; ++l) {
        gemm_alpha<<<(N_NODES + 31) / 32, 256, 0, stream>>>(cur, W[l], avs[l], avd[l], Hbuf, AS, AD);
        float* nxt = feat[l & 1];
        aggregate_kernel<<<(N_NODES + 3) / 4, 256, 0, stream>>>(Hbuf, AS, AD, offs, csr_src, bb[l], nxt);
        cur = nxt;
    }

    // global mean pool
    pool_kernel<<<N_GRAPHS, 512, 0, stream>>>(cur, start, (float*)d_out);
}

// Round 2
// 641.092 us; speedup vs baseline: 1.4645x; 1.4645x over previous
//
#include <hip/hip_runtime.h>
#include <math.h>

#define N_NODES 50000
#define N_GRAPHS 64
#define HID 128

typedef _Float16 half8 __attribute__((ext_vector_type(8)));
typedef float f32x4 __attribute__((ext_vector_type(4)));

__device__ __forceinline__ float lrelu(float e) { return e > 0.f ? e : 0.2f * e; }

// ---------------- CSR build ----------------
__global__ void count_kernel(const int* __restrict__ dst, int n_e, int* __restrict__ counts) {
    int e = blockIdx.x * blockDim.x + threadIdx.x;
    if (e < n_e) atomicAdd(&counts[dst[e]], 1);
}

__global__ __launch_bounds__(1024) void scan_kernel(const int* __restrict__ counts,
                                                    int* __restrict__ offs,
                                                    int* __restrict__ cursor) {
    __shared__ int part[1024];
    const int CH = (N_NODES + 1023) / 1024;  // 49
    int t = threadIdx.x;
    int base = t * CH;
    int s = 0;
    for (int i = 0; i < CH; ++i) {
        int idx = base + i;
        if (idx < N_NODES) s += counts[idx];
    }
    part[t] = s;
    __syncthreads();
    for (int off = 1; off < 1024; off <<= 1) {
        int v = (t >= off) ? part[t - off] : 0;
        __syncthreads();
        part[t] += v;
        __syncthreads();
    }
    int run = (t == 0) ? 0 : part[t - 1];
    for (int i = 0; i < CH; ++i) {
        int idx = base + i;
        if (idx < N_NODES) {
            offs[idx] = run;
            cursor[idx] = run;
            run += counts[idx];
        }
    }
    if (t == 0) offs[N_NODES] = part[1023];
}

__global__ void scatter_kernel(const int* __restrict__ src, const int* __restrict__ dst, int n_e,
                               int* __restrict__ cursor, int* __restrict__ csr_src) {
    int e = blockIdx.x * blockDim.x + threadIdx.x;
    if (e >= n_e) return;
    int d = dst[e];
    int pos = atomicAdd(&cursor[d], 1);
    csr_src[pos] = src[e];
}

// ---------------- graph boundary detection (batch sorted; no atomics) ----------------
__global__ void init_start(int* __restrict__ start) {
    int i = threadIdx.x;
    if (i < N_GRAPHS + 1) start[i] = N_NODES;
}

__global__ void find_start(const int* __restrict__ batch, int* __restrict__ start) {
    int i = blockIdx.x * blockDim.x + threadIdx.x;
    if (i >= N_NODES) return;
    int b = batch[i];
    if (i == 0) {
        start[b] = 0;
    } else {
        int pb = batch[i - 1];
        if (pb != b) start[b] = i;   // boundary: exactly one writer per graph
    }
}

__global__ void fix_start(int* __restrict__ start) {
    if (threadIdx.x == 0) {
        for (int g = N_GRAPHS - 1; g >= 0; --g)
            if (start[g] == N_NODES) start[g] = start[g + 1];
    }
}

// ---------------- W fragment packing (split-f16, MFMA B-operand layout) ----------------
// Layout: frag[((kt*8 + nt)*64 + lane)*8 + j] = W[(kt*32 + (lane>>4)*8 + j)*128 + nt*16 + (lane&15)]
__global__ void pack_w(const float* __restrict__ W, _Float16* __restrict__ Wh,
                       _Float16* __restrict__ Wl) {
    int t = blockIdx.x * blockDim.x + threadIdx.x;  // 0..2047
    if (t >= 2048) return;
    int lane = t & 63;
    int nt = (t >> 6) & 7;
    int kt = t >> 9;
    int n = nt * 16 + (lane & 15);
    int kbase = kt * 32 + (lane >> 4) * 8;
#pragma unroll
    for (int j = 0; j < 8; ++j) {
        float w = W[(size_t)(kbase + j) * 128 + n];
        _Float16 h = (_Float16)w;
        float r = w - (float)h;
        size_t idx = (size_t)t * 8 + j;
        Wh[idx] = h;
        Wl[idx] = (_Float16)r;
    }
}

// ---------------- MFMA GEMM + fused alpha: H = X@W, AS = H@a_src, AD = H@a_dst ----------------
// Block = 256 thr = 4 waves; wave computes 16 rows x 128 cols via 8 col-tiles of 16x16x32 f16.
// Split-f16: X@W ~= Xh@Wh + Xh@Wl + Xl@Wh (fp32 accum).
__global__ __launch_bounds__(256) void gemm_mfma(const float* __restrict__ X,
                                                 const _Float16* __restrict__ Wh,
                                                 const _Float16* __restrict__ Wl,
                                                 const float* __restrict__ a_s,
                                                 const float* __restrict__ a_d,
                                                 float* __restrict__ H,
                                                 float* __restrict__ AS,
                                                 float* __restrict__ AD) {
    int t = threadIdx.x;
    int wave = t >> 6, lane = t & 63;
    int m15 = lane & 15, quad = lane >> 4;
    int rowbase = blockIdx.x * 64 + wave * 16;
    int arow = rowbase + m15;              // row this lane loads for the A operand
    bool arow_ok = arow < N_NODES;

    f32x4 acc[8];
#pragma unroll
    for (int nt = 0; nt < 8; ++nt) acc[nt] = (f32x4){0.f, 0.f, 0.f, 0.f};

    const float* xrow = X + (size_t)arow * 128 + quad * 8;
#pragma unroll
    for (int kt = 0; kt < 4; ++kt) {
        f32x4 a0 = (f32x4){0.f, 0.f, 0.f, 0.f};
        f32x4 a1 = (f32x4){0.f, 0.f, 0.f, 0.f};
        if (arow_ok) {
            a0 = *(const f32x4*)(xrow + kt * 32);
            a1 = *(const f32x4*)(xrow + kt * 32 + 4);
        }
        half8 ah, al;
#pragma unroll
        for (int j = 0; j < 8; ++j) {
            float f = (j < 4) ? a0[j] : a1[j - 4];
            _Float16 h = (_Float16)f;
            ah[j] = h;
            al[j] = (_Float16)(f - (float)h);
        }
#pragma unroll
        for (int nt = 0; nt < 8; ++nt) {
            size_t fidx = ((size_t)((kt * 8 + nt) * 64 + lane)) * 8;
            half8 bh = *(const half8*)(Wh + fidx);
            half8 bl = *(const half8*)(Wl + fidx);
            acc[nt] = __builtin_amdgcn_mfma_f32_16x16x32_f16(ah, bh, acc[nt], 0, 0, 0);
            acc[nt] = __builtin_amdgcn_mfma_f32_16x16x32_f16(ah, bl, acc[nt], 0, 0, 0);
            acc[nt] = __builtin_amdgcn_mfma_f32_16x16x32_f16(al, bh, acc[nt], 0, 0, 0);
        }
    }

    // epilogue: C/D layout col = nt*16 + m15, row = quad*4 + reg
    float as_acc[4] = {0.f, 0.f, 0.f, 0.f};
    float ad_acc[4] = {0.f, 0.f, 0.f, 0.f};
#pragma unroll
    for (int nt = 0; nt < 8; ++nt) {
        int c = nt * 16 + m15;
        float cas = a_s[c];
        float cad = a_d[c];
#pragma unroll
        for (int reg = 0; reg < 4; ++reg) {
            float v = acc[nt][reg];
            as_acc[reg] += v * cas;
            ad_acc[reg] += v * cad;
            int gr = rowbase + quad * 4 + reg;
            if (gr < N_NODES) H[(size_t)gr * 128 + c] = v;
        }
    }
#pragma unroll
    for (int off = 1; off < 16; off <<= 1) {
#pragma unroll
        for (int reg = 0; reg < 4; ++reg) {
            as_acc[reg] += __shfl_xor(as_acc[reg], off);
            ad_acc[reg] += __shfl_xor(ad_acc[reg], off);
        }
    }
    if (m15 == 0) {
#pragma unroll
        for (int reg = 0; reg < 4; ++reg) {
            int gr = rowbase + quad * 4 + reg;
            if (gr < N_NODES) { AS[gr] = as_acc[reg]; AD[gr] = ad_acc[reg]; }
        }
    }
}

// ---------------- attention + aggregation: one wave per dst node ----------------
__global__ __launch_bounds__(256) void aggregate_kernel(const float* __restrict__ H,
                                                        const float* __restrict__ AS,
                                                        const float* __restrict__ AD,
                                                        const int* __restrict__ offs,
                                                        const int* __restrict__ csr_src,
                                                        const float* __restrict__ bias,
                                                        float* __restrict__ OUT) {
    int node = blockIdx.x * 4 + (threadIdx.x >> 6);
    if (node >= N_NODES) return;
    int lane = threadIdx.x & 63;
    int beg = offs[node], end = offs[node + 1];
    float ad = AD[node];
    float eself = lrelu(AS[node] + ad);

    float mym = -INFINITY;
    for (int i = beg + lane; i < end; i += 64) {
        int s = csr_src[i];
        mym = fmaxf(mym, lrelu(AS[s] + ad));
    }
#pragma unroll
    for (int off = 32; off; off >>= 1) mym = fmaxf(mym, __shfl_xor(mym, off));
    float m = fmaxf(mym, eself);

    float ssum = 0.f;
    for (int i = beg + lane; i < end; i += 64) {
        int s = csr_src[i];
        ssum += expf(lrelu(AS[s] + ad) - m);
    }
#pragma unroll
    for (int off = 32; off; off >>= 1) ssum += __shfl_xor(ssum, off);
    ssum += expf(eself - m);
    float inv = 1.f / (ssum + 1e-16f);

    float acc0 = 0.f, acc1 = 0.f;
    for (int i = beg; i < end; ++i) {
        int s = csr_src[i];
        float coef = expf(lrelu(AS[s] + ad) - m);
        acc0 = fmaf(coef, H[(size_t)s * 128 + lane], acc0);
        acc1 = fmaf(coef, H[(size_t)s * 128 + 64 + lane], acc1);
    }
    {
        float coef = expf(eself - m);
        acc0 = fmaf(coef, H[(size_t)node * 128 + lane], acc0);
        acc1 = fmaf(coef, H[(size_t)node * 128 + 64 + lane], acc1);
    }
    float o0 = acc0 * inv + bias[lane];
    float o1 = acc1 * inv + bias[lane + 64];
    o0 = o0 > 0.f ? o0 : expm1f(o0);
    o1 = o1 > 0.f ? o1 : expm1f(o1);
    OUT[(size_t)node * 128 + lane] = o0;
    OUT[(size_t)node * 128 + 64 + lane] = o1;
}

// ---------------- global mean pool ----------------
__global__ __launch_bounds__(512) void pool_kernel(const float* __restrict__ F,
                                                   const int* __restrict__ start,
                                                   float* __restrict__ out) {
    __shared__ float red[512];
    int g = blockIdx.x;
    int t = threadIdx.x;
    int c = t & 127, sub = t >> 7;
    int b = start[g], e = start[g + 1];
    float acc = 0.f;
    for (int i = b + sub; i < e; i += 4) acc += F[(size_t)i * 128 + c];
    red[t] = acc;
    __syncthreads();
    if (sub == 0) {
        float v = red[c] + red[c + 128] + red[c + 256] + red[c + 384];
        int cnt = e - b;
        out[(size_t)g * 128 + c] = v / (float)(cnt > 1 ? cnt : 1);
    }
}

extern "C" void kernel_launch(void* const* d_in, const int* in_sizes, int n_in,
                              void* d_out, int out_size, void* d_ws, size_t ws_size,
                              hipStream_t stream) {
    const float* x = (const float*)d_in[0];
    const int* edge_index = (const int*)d_in[1];
    const int* batch = (const int*)d_in[2];
    const float* W[3]   = {(const float*)d_in[3], (const float*)d_in[7], (const float*)d_in[11]};
    const float* avs[3] = {(const float*)d_in[4], (const float*)d_in[8], (const float*)d_in[12]};
    const float* avd[3] = {(const float*)d_in[5], (const float*)d_in[9], (const float*)d_in[13]};
    const float* bb[3]  = {(const float*)d_in[6], (const float*)d_in[10], (const float*)d_in[14]};
    int E0 = in_sizes[1] / 2;
    const int* esrc = edge_index;
    const int* edst = edge_index + E0;

    char* p = (char*)d_ws;
    auto alloc = [&](size_t bytes) -> void* {
        void* q = (void*)p;
        p += (bytes + 255) & ~(size_t)255;
        return q;
    };
    int* counts   = (int*)alloc((size_t)N_NODES * 4);
    int* offs     = (int*)alloc((size_t)(N_NODES + 1) * 4);
    int* cursor   = (int*)alloc((size_t)N_NODES * 4);
    int* csr_src  = (int*)alloc((size_t)E0 * 4);
    int* start    = (int*)alloc((N_GRAPHS + 1) * 4);
    float* AS     = (float*)alloc((size_t)N_NODES * 4);
    float* AD     = (float*)alloc((size_t)N_NODES * 4);
    float* Hbuf   = (float*)alloc((size_t)N_NODES * HID * 4);
    float* FA     = (float*)alloc((size_t)N_NODES * HID * 4);
    float* FB     = (float*)alloc((size_t)N_NODES * HID * 4);
    _Float16* Wh[3], *Wl[3];
    for (int l = 0; l < 3; ++l) {
        Wh[l] = (_Float16*)alloc(16384 * 2);
        Wl[l] = (_Float16*)alloc(16384 * 2);
    }

    // CSR build
    hipMemsetAsync(counts, 0, (size_t)N_NODES * 4, stream);
    count_kernel<<<(E0 + 255) / 256, 256, 0, stream>>>(edst, E0, counts);
    scan_kernel<<<1, 1024, 0, stream>>>(counts, offs, cursor);
    scatter_kernel<<<(E0 + 255) / 256, 256, 0, stream>>>(esrc, edst, E0, cursor, csr_src);

    // graph boundaries (no atomics)
    init_start<<<1, 128, 0, stream>>>(start);
    find_start<<<(N_NODES + 255) / 256, 256, 0, stream>>>(batch, start);
    fix_start<<<1, 64, 0, stream>>>(start);

    // W fragment packing (split-f16)
    for (int l = 0; l < 3; ++l)
        pack_w<<<8, 256, 0, stream>>>(W[l], Wh[l], Wl[l]);

    // 3 GAT layers
    const float* cur = x;
    float* feat[2] = {FA, FB};
    for (int l = 0; l < 3; ++l) {
        gemm_mfma<<<(N_NODES + 63) / 64, 256, 0, stream>>>(cur, Wh[l], Wl[l], avs[l], avd[l],
                                                           Hbuf, AS, AD);
        float* nxt = feat[l & 1];
        aggregate_kernel<<<(N_NODES + 3) / 4, 256, 0, stream>>>(Hbuf, AS, AD, offs, csr_src,
                                                                bb[l], nxt);
        cur = nxt;
    }

    pool_kernel<<<N_GRAPHS, 512, 0, stream>>>(cur, start, (float*)d_out);
}

// Round 3
// 430.911 us; speedup vs baseline: 2.1789x; 1.4878x over previous
//
#include <hip/hip_runtime.h>
#include <math.h>

#define N_NODES 50000
#define N_GRAPHS 64
#define HID 128
#define SCAN_B 196  // ceil(50000/256)

typedef _Float16 half8 __attribute__((ext_vector_type(8)));
typedef float f32x4 __attribute__((ext_vector_type(4)));

__device__ __forceinline__ float lrelu(float e) { return e > 0.f ? e : 0.2f * e; }

// ---------------- CSR build ----------------
__global__ void count_kernel(const int* __restrict__ dst, int n_e, int* __restrict__ counts) {
    int e = blockIdx.x * blockDim.x + threadIdx.x;
    if (e < n_e) atomicAdd(&counts[dst[e]], 1);
}

// 3-phase parallel exclusive scan of counts -> offs (+cursor copy)
__global__ __launch_bounds__(256) void block_reduce(const int* __restrict__ counts,
                                                    int* __restrict__ bsum) {
    __shared__ int red[256];
    int t = threadIdx.x;
    int i = blockIdx.x * 256 + t;
    red[t] = (i < N_NODES) ? counts[i] : 0;
    __syncthreads();
#pragma unroll
    for (int off = 128; off; off >>= 1) {
        if (t < off) red[t] += red[t + off];
        __syncthreads();
    }
    if (t == 0) bsum[blockIdx.x] = red[0];
}

__global__ __launch_bounds__(256) void scan_bsum(const int* __restrict__ bsum,
                                                 int* __restrict__ bpre,
                                                 int* __restrict__ offs) {
    __shared__ int sh[256];
    int t = threadIdx.x;
    int v = (t < SCAN_B) ? bsum[t] : 0;
    sh[t] = v;
    __syncthreads();
#pragma unroll
    for (int off = 1; off < 256; off <<= 1) {
        int u = (t >= off) ? sh[t - off] : 0;
        __syncthreads();
        sh[t] += u;
        __syncthreads();
    }
    if (t < SCAN_B) bpre[t] = sh[t] - v;
    if (t == SCAN_B - 1) offs[N_NODES] = sh[t];
}

__global__ __launch_bounds__(256) void block_scan(const int* __restrict__ counts,
                                                  const int* __restrict__ bpre,
                                                  int* __restrict__ offs,
                                                  int* __restrict__ cursor) {
    __shared__ int sh[256];
    int t = threadIdx.x;
    int i = blockIdx.x * 256 + t;
    int c = (i < N_NODES) ? counts[i] : 0;
    sh[t] = c;
    __syncthreads();
#pragma unroll
    for (int off = 1; off < 256; off <<= 1) {
        int u = (t >= off) ? sh[t - off] : 0;
        __syncthreads();
        sh[t] += u;
        __syncthreads();
    }
    if (i < N_NODES) {
        int e = bpre[blockIdx.x] + sh[t] - c;  // exclusive prefix
        offs[i] = e;
        cursor[i] = e;
    }
}

__global__ void scatter_kernel(const int* __restrict__ src, const int* __restrict__ dst, int n_e,
                               int* __restrict__ cursor, int* __restrict__ csr_src) {
    int e = blockIdx.x * blockDim.x + threadIdx.x;
    if (e >= n_e) return;
    int d = dst[e];
    int pos = atomicAdd(&cursor[d], 1);
    csr_src[pos] = src[e];
}

// ---------------- graph boundary detection (batch sorted; no atomics) ----------------
__global__ void init_start(int* __restrict__ start) {
    int i = threadIdx.x;
    if (i < N_GRAPHS + 1) start[i] = N_NODES;
}

__global__ void find_start(const int* __restrict__ batch, int* __restrict__ start) {
    int i = blockIdx.x * blockDim.x + threadIdx.x;
    if (i >= N_NODES) return;
    int b = batch[i];
    if (i == 0) {
        start[b] = 0;
    } else {
        int pb = batch[i - 1];
        if (pb != b) start[b] = i;
    }
}

__global__ void fix_start(int* __restrict__ start) {
    if (threadIdx.x == 0) {
        for (int g = N_GRAPHS - 1; g >= 0; --g)
            if (start[g] == N_NODES) start[g] = start[g + 1];
    }
}

// ---------------- W fragment packing, all 3 layers in one launch ----------------
// frag[((kt*8 + nt)*64 + lane)*8 + j] = W[(kt*32 + (lane>>4)*8 + j)*128 + nt*16 + (lane&15)]
__global__ void pack_w3(const float* __restrict__ W0, const float* __restrict__ W1,
                        const float* __restrict__ W2,
                        _Float16* __restrict__ Wh0, _Float16* __restrict__ Wl0,
                        _Float16* __restrict__ Wh1, _Float16* __restrict__ Wl1,
                        _Float16* __restrict__ Wh2, _Float16* __restrict__ Wl2) {
    int layer = blockIdx.x >> 3;
    const float* W = layer == 0 ? W0 : (layer == 1 ? W1 : W2);
    _Float16* Wh = layer == 0 ? Wh0 : (layer == 1 ? Wh1 : Wh2);
    _Float16* Wl = layer == 0 ? Wl0 : (layer == 1 ? Wl1 : Wl2);
    int t = (blockIdx.x & 7) * 256 + threadIdx.x;  // 0..2047
    int lane = t & 63;
    int nt = (t >> 6) & 7;
    int kt = t >> 9;
    int n = nt * 16 + (lane & 15);
    int kbase = kt * 32 + (lane >> 4) * 8;
#pragma unroll
    for (int j = 0; j < 8; ++j) {
        float w = W[(size_t)(kbase + j) * 128 + n];
        _Float16 h = (_Float16)w;
        float r = w - (float)h;
        size_t idx = (size_t)t * 8 + j;
        Wh[idx] = h;
        Wl[idx] = (_Float16)r;
    }
}

// ---------------- MFMA GEMM + fused alpha: H = X@W, AS = H@a_src, AD = H@a_dst ----------------
__global__ __launch_bounds__(256) void gemm_mfma(const float* __restrict__ X,
                                                 const _Float16* __restrict__ Wh,
                                                 const _Float16* __restrict__ Wl,
                                                 const float* __restrict__ a_s,
                                                 const float* __restrict__ a_d,
                                                 float* __restrict__ H,
                                                 float* __restrict__ AS,
                                                 float* __restrict__ AD) {
    int t = threadIdx.x;
    int wave = t >> 6, lane = t & 63;
    int m15 = lane & 15, quad = lane >> 4;
    int rowbase = blockIdx.x * 64 + wave * 16;
    int arow = rowbase + m15;
    bool arow_ok = arow < N_NODES;

    f32x4 acc[8];
#pragma unroll
    for (int nt = 0; nt < 8; ++nt) acc[nt] = (f32x4){0.f, 0.f, 0.f, 0.f};

    const float* xrow = X + (size_t)arow * 128 + quad * 8;
#pragma unroll
    for (int kt = 0; kt < 4; ++kt) {
        f32x4 a0 = (f32x4){0.f, 0.f, 0.f, 0.f};
        f32x4 a1 = (f32x4){0.f, 0.f, 0.f, 0.f};
        if (arow_ok) {
            a0 = *(const f32x4*)(xrow + kt * 32);
            a1 = *(const f32x4*)(xrow + kt * 32 + 4);
        }
        half8 ah, al;
#pragma unroll
        for (int j = 0; j < 8; ++j) {
            float f = (j < 4) ? a0[j] : a1[j - 4];
            _Float16 h = (_Float16)f;
            ah[j] = h;
            al[j] = (_Float16)(f - (float)h);
        }
#pragma unroll
        for (int nt = 0; nt < 8; ++nt) {
            size_t fidx = ((size_t)((kt * 8 + nt) * 64 + lane)) * 8;
            half8 bh = *(const half8*)(Wh + fidx);
            half8 bl = *(const half8*)(Wl + fidx);
            acc[nt] = __builtin_amdgcn_mfma_f32_16x16x32_f16(ah, bh, acc[nt], 0, 0, 0);
            acc[nt] = __builtin_amdgcn_mfma_f32_16x16x32_f16(ah, bl, acc[nt], 0, 0, 0);
            acc[nt] = __builtin_amdgcn_mfma_f32_16x16x32_f16(al, bh, acc[nt], 0, 0, 0);
        }
    }

    float as_acc[4] = {0.f, 0.f, 0.f, 0.f};
    float ad_acc[4] = {0.f, 0.f, 0.f, 0.f};
#pragma unroll
    for (int nt = 0; nt < 8; ++nt) {
        int c = nt * 16 + m15;
        float cas = a_s[c];
        float cad = a_d[c];
#pragma unroll
        for (int reg = 0; reg < 4; ++reg) {
            float v = acc[nt][reg];
            as_acc[reg] += v * cas;
            ad_acc[reg] += v * cad;
            int gr = rowbase + quad * 4 + reg;
            if (gr < N_NODES) H[(size_t)gr * 128 + c] = v;
        }
    }
#pragma unroll
    for (int off = 1; off < 16; off <<= 1) {
#pragma unroll
        for (int reg = 0; reg < 4; ++reg) {
            as_acc[reg] += __shfl_xor(as_acc[reg], off);
            ad_acc[reg] += __shfl_xor(ad_acc[reg], off);
        }
    }
    if (m15 == 0) {
#pragma unroll
        for (int reg = 0; reg < 4; ++reg) {
            int gr = rowbase + quad * 4 + reg;
            if (gr < N_NODES) { AS[gr] = as_acc[reg]; AD[gr] = ad_acc[reg]; }
        }
    }
}

// ---------------- attention + aggregation: one wave per dst node ----------------
// Fast path (deg<=64): per-lane cached src & p=exp(e-m); shfl-broadcast in gather.
__global__ __launch_bounds__(256) void aggregate_kernel(const float* __restrict__ H,
                                                        const float* __restrict__ AS,
                                                        const float* __restrict__ AD,
                                                        const int* __restrict__ offs,
                                                        const int* __restrict__ csr_src,
                                                        const float* __restrict__ bias,
                                                        float* __restrict__ OUT) {
    int node = blockIdx.x * 4 + (threadIdx.x >> 6);
    if (node >= N_NODES) return;
    int lane = threadIdx.x & 63;
    int beg = offs[node], end = offs[node + 1];
    int deg = end - beg;
    float ad = AD[node];
    float eself = lrelu(AS[node] + ad);
    const float2* H2 = (const float2*)H;

    float ax = 0.f, ay = 0.f;   // accumulator chain 0
    float bx = 0.f, by = 0.f;   // accumulator chain 1
    float inv, pself;

    if (deg <= 64) {
        int s = node;
        float ev = -INFINITY;
        if (lane < deg) {
            s = csr_src[beg + lane];
            ev = lrelu(AS[s] + ad);
        }
        float m = ev;
#pragma unroll
        for (int off = 32; off; off >>= 1) m = fmaxf(m, __shfl_xor(m, off));
        m = fmaxf(m, eself);
        float p = (lane < deg) ? expf(ev - m) : 0.f;
        float ssum = p;
#pragma unroll
        for (int off = 32; off; off >>= 1) ssum += __shfl_xor(ssum, off);
        pself = expf(eself - m);
        ssum += pself;
        inv = 1.f / (ssum + 1e-16f);

        int k = 0;
        for (; k + 1 < deg; k += 2) {
            int s0 = __shfl(s, k), s1 = __shfl(s, k + 1);
            float c0 = __shfl(p, k), c1 = __shfl(p, k + 1);
            float2 h0 = H2[(size_t)s0 * 64 + lane];
            float2 h1 = H2[(size_t)s1 * 64 + lane];
            ax = fmaf(c0, h0.x, ax); ay = fmaf(c0, h0.y, ay);
            bx = fmaf(c1, h1.x, bx); by = fmaf(c1, h1.y, by);
        }
        if (k < deg) {
            int s0 = __shfl(s, k);
            float c0 = __shfl(p, k);
            float2 h0 = H2[(size_t)s0 * 64 + lane];
            ax = fmaf(c0, h0.x, ax); ay = fmaf(c0, h0.y, ay);
        }
    } else {
        float mym = -INFINITY;
        for (int i = beg + lane; i < end; i += 64)
            mym = fmaxf(mym, lrelu(AS[csr_src[i]] + ad));
#pragma unroll
        for (int off = 32; off; off >>= 1) mym = fmaxf(mym, __shfl_xor(mym, off));
        float m = fmaxf(mym, eself);
        float ssum = 0.f;
        for (int i = beg + lane; i < end; i += 64)
            ssum += expf(lrelu(AS[csr_src[i]] + ad) - m);
#pragma unroll
        for (int off = 32; off; off >>= 1) ssum += __shfl_xor(ssum, off);
        pself = expf(eself - m);
        ssum += pself;
        inv = 1.f / (ssum + 1e-16f);
        for (int i = beg; i < end; ++i) {
            int s = csr_src[i];
            float coef = expf(lrelu(AS[s] + ad) - m);
            float2 h0 = H2[(size_t)s * 64 + lane];
            ax = fmaf(coef, h0.x, ax); ay = fmaf(coef, h0.y, ay);
        }
    }

    float2 hs = H2[(size_t)node * 64 + lane];
    ax = fmaf(pself, hs.x, ax) + bx;
    ay = fmaf(pself, hs.y, ay) + by;
    float2 b2 = ((const float2*)bias)[lane];
    float o0 = ax * inv + b2.x;
    float o1 = ay * inv + b2.y;
    o0 = o0 > 0.f ? o0 : expm1f(o0);
    o1 = o1 > 0.f ? o1 : expm1f(o1);
    float2 o = make_float2(o0, o1);
    ((float2*)OUT)[(size_t)node * 64 + lane] = o;
}

// ---------------- global mean pool ----------------
__global__ __launch_bounds__(512) void pool_kernel(const float* __restrict__ F,
                                                   const int* __restrict__ start,
                                                   float* __restrict__ out) {
    __shared__ float red[512];
    int g = blockIdx.x;
    int t = threadIdx.x;
    int c = t & 127, sub = t >> 7;
    int b = start[g], e = start[g + 1];
    float acc = 0.f;
    for (int i = b + sub; i < e; i += 4) acc += F[(size_t)i * 128 + c];
    red[t] = acc;
    __syncthreads();
    if (sub == 0) {
        float v = red[c] + red[c + 128] + red[c + 256] + red[c + 384];
        int cnt = e - b;
        out[(size_t)g * 128 + c] = v / (float)(cnt > 1 ? cnt : 1);
    }
}

extern "C" void kernel_launch(void* const* d_in, const int* in_sizes, int n_in,
                              void* d_out, int out_size, void* d_ws, size_t ws_size,
                              hipStream_t stream) {
    const float* x = (const float*)d_in[0];
    const int* edge_index = (const int*)d_in[1];
    const int* batch = (const int*)d_in[2];
    const float* W[3]   = {(const float*)d_in[3], (const float*)d_in[7], (const float*)d_in[11]};
    const float* avs[3] = {(const float*)d_in[4], (const float*)d_in[8], (const float*)d_in[12]};
    const float* avd[3] = {(const float*)d_in[5], (const float*)d_in[9], (const float*)d_in[13]};
    const float* bb[3]  = {(const float*)d_in[6], (const float*)d_in[10], (const float*)d_in[14]};
    int E0 = in_sizes[1] / 2;
    const int* esrc = edge_index;
    const int* edst = edge_index + E0;

    char* p = (char*)d_ws;
    auto alloc = [&](size_t bytes) -> void* {
        void* q = (void*)p;
        p += (bytes + 255) & ~(size_t)255;
        return q;
    };
    int* counts   = (int*)alloc((size_t)N_NODES * 4);
    int* offs     = (int*)alloc((size_t)(N_NODES + 1) * 4);
    int* cursor   = (int*)alloc((size_t)N_NODES * 4);
    int* csr_src  = (int*)alloc((size_t)E0 * 4);
    int* start    = (int*)alloc((N_GRAPHS + 1) * 4);
    int* bsum     = (int*)alloc(SCAN_B * 4);
    int* bpre     = (int*)alloc(SCAN_B * 4);
    float* AS     = (float*)alloc((size_t)N_NODES * 4);
    float* AD     = (float*)alloc((size_t)N_NODES * 4);
    float* Hbuf   = (float*)alloc((size_t)N_NODES * HID * 4);
    float* FA     = (float*)alloc((size_t)N_NODES * HID * 4);
    float* FB     = (float*)alloc((size_t)N_NODES * HID * 4);
    _Float16* Wh[3], *Wl[3];
    for (int l = 0; l < 3; ++l) {
        Wh[l] = (_Float16*)alloc(16384 * 2);
        Wl[l] = (_Float16*)alloc(16384 * 2);
    }

    // CSR build (parallel scan)
    hipMemsetAsync(counts, 0, (size_t)N_NODES * 4, stream);
    count_kernel<<<(E0 + 255) / 256, 256, 0, stream>>>(edst, E0, counts);
    block_reduce<<<SCAN_B, 256, 0, stream>>>(counts, bsum);
    scan_bsum<<<1, 256, 0, stream>>>(bsum, bpre, offs);
    block_scan<<<SCAN_B, 256, 0, stream>>>(counts, bpre, offs, cursor);
    scatter_kernel<<<(E0 + 255) / 256, 256, 0, stream>>>(esrc, edst, E0, cursor, csr_src);

    // graph boundaries
    init_start<<<1, 128, 0, stream>>>(start);
    find_start<<<(N_NODES + 255) / 256, 256, 0, stream>>>(batch, start);
    fix_start<<<1, 64, 0, stream>>>(start);

    // W fragment packing (split-f16), all layers
    pack_w3<<<24, 256, 0, stream>>>(W[0], W[1], W[2], Wh[0], Wl[0], Wh[1], Wl[1], Wh[2], Wl[2]);

    // 3 GAT layers
    const float* cur = x;
    float* feat[2] = {FA, FB};
    for (int l = 0; l < 3; ++l) {
        gemm_mfma<<<(N_NODES + 63) / 64, 256, 0, stream>>>(cur, Wh[l], Wl[l], avs[l], avd[l],
                                                           Hbuf, AS, AD);
        float* nxt = feat[l & 1];
        aggregate_kernel<<<(N_NODES + 3) / 4, 256, 0, stream>>>(Hbuf, AS, AD, offs, csr_src,
                                                                bb[l], nxt);
        cur = nxt;
    }

    pool_kernel<<<N_GRAPHS, 512, 0, stream>>>(cur, start, (float*)d_out);
}

// Round 4
// 402.121 us; speedup vs baseline: 2.3348x; 1.0716x over previous
//
#include <hip/hip_runtime.h>
#include <math.h>

#define N_NODES 50000
#define N_GRAPHS 64
#define HID 128
#define SCAN_B 196  // ceil(50000/256)

typedef _Float16 half8 __attribute__((ext_vector_type(8)));
typedef float f32x4 __attribute__((ext_vector_type(4)));

__device__ __forceinline__ float lrelu(float e) { return e > 0.f ? e : 0.2f * e; }

// ---------------- CSR build ----------------
__global__ void count_kernel(const int* __restrict__ dst, int n_e, int* __restrict__ counts) {
    int e = blockIdx.x * blockDim.x + threadIdx.x;
    if (e < n_e) atomicAdd(&counts[dst[e]], 1);
}

__global__ __launch_bounds__(256) void block_reduce(const int* __restrict__ counts,
                                                    int* __restrict__ bsum) {
    __shared__ int red[256];
    int t = threadIdx.x;
    int i = blockIdx.x * 256 + t;
    red[t] = (i < N_NODES) ? counts[i] : 0;
    __syncthreads();
#pragma unroll
    for (int off = 128; off; off >>= 1) {
        if (t < off) red[t] += red[t + off];
        __syncthreads();
    }
    if (t == 0) bsum[blockIdx.x] = red[0];
}

__global__ __launch_bounds__(256) void scan_bsum(const int* __restrict__ bsum,
                                                 int* __restrict__ bpre,
                                                 int* __restrict__ offs) {
    __shared__ int sh[256];
    int t = threadIdx.x;
    int v = (t < SCAN_B) ? bsum[t] : 0;
    sh[t] = v;
    __syncthreads();
#pragma unroll
    for (int off = 1; off < 256; off <<= 1) {
        int u = (t >= off) ? sh[t - off] : 0;
        __syncthreads();
        sh[t] += u;
        __syncthreads();
    }
    if (t < SCAN_B) bpre[t] = sh[t] - v;
    if (t == SCAN_B - 1) offs[N_NODES] = sh[t];
}

__global__ __launch_bounds__(256) void block_scan(const int* __restrict__ counts,
                                                  const int* __restrict__ bpre,
                                                  int* __restrict__ offs,
                                                  int* __restrict__ cursor) {
    __shared__ int sh[256];
    int t = threadIdx.x;
    int i = blockIdx.x * 256 + t;
    int c = (i < N_NODES) ? counts[i] : 0;
    sh[t] = c;
    __syncthreads();
#pragma unroll
    for (int off = 1; off < 256; off <<= 1) {
        int u = (t >= off) ? sh[t - off] : 0;
        __syncthreads();
        sh[t] += u;
        __syncthreads();
    }
    if (i < N_NODES) {
        int e = bpre[blockIdx.x] + sh[t] - c;
        offs[i] = e;
        cursor[i] = e;
    }
}

__global__ void scatter_kernel(const int* __restrict__ src, const int* __restrict__ dst, int n_e,
                               int* __restrict__ cursor, int* __restrict__ csr_src) {
    int e = blockIdx.x * blockDim.x + threadIdx.x;
    if (e >= n_e) return;
    int d = dst[e];
    int pos = atomicAdd(&cursor[d], 1);
    csr_src[pos] = src[e];
}

// ---------------- graph boundary detection ----------------
__global__ void init_start(int* __restrict__ start) {
    int i = threadIdx.x;
    if (i < N_GRAPHS + 1) start[i] = N_NODES;
}

__global__ void find_start(const int* __restrict__ batch, int* __restrict__ start) {
    int i = blockIdx.x * blockDim.x + threadIdx.x;
    if (i >= N_NODES) return;
    int b = batch[i];
    if (i == 0) {
        start[b] = 0;
    } else {
        int pb = batch[i - 1];
        if (pb != b) start[b] = i;
    }
}

__global__ void fix_start(int* __restrict__ start) {
    if (threadIdx.x == 0) {
        for (int g = N_GRAPHS - 1; g >= 0; --g)
            if (start[g] == N_NODES) start[g] = start[g + 1];
    }
}

// ---------------- W fragment packing (split-f16) ----------------
__global__ void pack_w3(const float* __restrict__ W0, const float* __restrict__ W1,
                        const float* __restrict__ W2,
                        _Float16* __restrict__ Wh0, _Float16* __restrict__ Wl0,
                        _Float16* __restrict__ Wh1, _Float16* __restrict__ Wl1,
                        _Float16* __restrict__ Wh2, _Float16* __restrict__ Wl2) {
    int layer = blockIdx.x >> 3;
    const float* W = layer == 0 ? W0 : (layer == 1 ? W1 : W2);
    _Float16* Wh = layer == 0 ? Wh0 : (layer == 1 ? Wh1 : Wh2);
    _Float16* Wl = layer == 0 ? Wl0 : (layer == 1 ? Wl1 : Wl2);
    int t = (blockIdx.x & 7) * 256 + threadIdx.x;
    int lane = t & 63;
    int nt = (t >> 6) & 7;
    int kt = t >> 9;
    int n = nt * 16 + (lane & 15);
    int kbase = kt * 32 + (lane >> 4) * 8;
#pragma unroll
    for (int j = 0; j < 8; ++j) {
        float w = W[(size_t)(kbase + j) * 128 + n];
        _Float16 h = (_Float16)w;
        float r = w - (float)h;
        size_t idx = (size_t)t * 8 + j;
        Wh[idx] = h;
        Wl[idx] = (_Float16)r;
    }
}

// ---------------- MFMA GEMM + fused alpha ----------------
__global__ __launch_bounds__(256) void gemm_mfma(const float* __restrict__ X,
                                                 const _Float16* __restrict__ Wh,
                                                 const _Float16* __restrict__ Wl,
                                                 const float* __restrict__ a_s,
                                                 const float* __restrict__ a_d,
                                                 float* __restrict__ H,
                                                 float* __restrict__ AS,
                                                 float* __restrict__ AD) {
    int t = threadIdx.x;
    int wave = t >> 6, lane = t & 63;
    int m15 = lane & 15, quad = lane >> 4;
    int rowbase = blockIdx.x * 64 + wave * 16;
    int arow = rowbase + m15;
    bool arow_ok = arow < N_NODES;

    f32x4 acc[8];
#pragma unroll
    for (int nt = 0; nt < 8; ++nt) acc[nt] = (f32x4){0.f, 0.f, 0.f, 0.f};

    const float* xrow = X + (size_t)arow * 128 + quad * 8;
#pragma unroll
    for (int kt = 0; kt < 4; ++kt) {
        f32x4 a0 = (f32x4){0.f, 0.f, 0.f, 0.f};
        f32x4 a1 = (f32x4){0.f, 0.f, 0.f, 0.f};
        if (arow_ok) {
            a0 = *(const f32x4*)(xrow + kt * 32);
            a1 = *(const f32x4*)(xrow + kt * 32 + 4);
        }
        half8 ah, al;
#pragma unroll
        for (int j = 0; j < 8; ++j) {
            float f = (j < 4) ? a0[j] : a1[j - 4];
            _Float16 h = (_Float16)f;
            ah[j] = h;
            al[j] = (_Float16)(f - (float)h);
        }
#pragma unroll
        for (int nt = 0; nt < 8; ++nt) {
            size_t fidx = ((size_t)((kt * 8 + nt) * 64 + lane)) * 8;
            half8 bh = *(const half8*)(Wh + fidx);
            half8 bl = *(const half8*)(Wl + fidx);
            acc[nt] = __builtin_amdgcn_mfma_f32_16x16x32_f16(ah, bh, acc[nt], 0, 0, 0);
            acc[nt] = __builtin_amdgcn_mfma_f32_16x16x32_f16(ah, bl, acc[nt], 0, 0, 0);
            acc[nt] = __builtin_amdgcn_mfma_f32_16x16x32_f16(al, bh, acc[nt], 0, 0, 0);
        }
    }

    float as_acc[4] = {0.f, 0.f, 0.f, 0.f};
    float ad_acc[4] = {0.f, 0.f, 0.f, 0.f};
#pragma unroll
    for (int nt = 0; nt < 8; ++nt) {
        int c = nt * 16 + m15;
        float cas = a_s[c];
        float cad = a_d[c];
#pragma unroll
        for (int reg = 0; reg < 4; ++reg) {
            float v = acc[nt][reg];
            as_acc[reg] += v * cas;
            ad_acc[reg] += v * cad;
            int gr = rowbase + quad * 4 + reg;
            if (gr < N_NODES) H[(size_t)gr * 128 + c] = v;
        }
    }
#pragma unroll
    for (int off = 1; off < 16; off <<= 1) {
#pragma unroll
        for (int reg = 0; reg < 4; ++reg) {
            as_acc[reg] += __shfl_xor(as_acc[reg], off);
            ad_acc[reg] += __shfl_xor(ad_acc[reg], off);
        }
    }
    if (m15 == 0) {
#pragma unroll
        for (int reg = 0; reg < 4; ++reg) {
            int gr = rowbase + quad * 4 + reg;
            if (gr < N_NODES) { AS[gr] = as_acc[reg]; AD[gr] = ad_acc[reg]; }
        }
    }
}

// ---------------- attention + aggregation: one wave per dst node ----------------
// float4 half-wave gather: row = 32 lanes x 16B; lanes 0-31 even edges, 32-63 odd.
__global__ __launch_bounds__(256) void aggregate_kernel(const float* __restrict__ H,
                                                        const float* __restrict__ AS,
                                                        const float* __restrict__ AD,
                                                        const int* __restrict__ offs,
                                                        const int* __restrict__ csr_src,
                                                        const float* __restrict__ bias,
                                                        float* __restrict__ OUT) {
    int node = blockIdx.x * 4 + (threadIdx.x >> 6);
    if (node >= N_NODES) return;
    int lane = threadIdx.x & 63;
    int half = lane >> 5, l32 = lane & 31;
    int beg = offs[node], end = offs[node + 1];
    int deg = end - beg;
    float ad = AD[node];
    float eself = lrelu(AS[node] + ad);
    const f32x4* H4 = (const f32x4*)H;

    float inv, pself;
    f32x4 a0 = (f32x4){0.f, 0.f, 0.f, 0.f};
    f32x4 a1 = a0, a2 = a0, a3 = a0;

    if (deg <= 64) {
        int s = node;
        float ev = -INFINITY;
        if (lane < deg) {
            s = csr_src[beg + lane];
            ev = lrelu(AS[s] + ad);
        }
        float m = ev;
#pragma unroll
        for (int off = 32; off; off >>= 1) m = fmaxf(m, __shfl_xor(m, off));
        m = fmaxf(m, eself);
        float p = (lane < deg) ? expf(ev - m) : 0.f;
        float ssum = p;
#pragma unroll
        for (int off = 32; off; off >>= 1) ssum += __shfl_xor(ssum, off);
        pself = expf(eself - m);
        ssum += pself;
        inv = 1.f / (ssum + 1e-16f);

        for (int kb = 0; kb < deg; kb += 8) {
            int i0 = kb + half;          // edges kb+0 / kb+1 per half
            int i1 = kb + 2 + half;
            int i2 = kb + 4 + half;
            int i3 = kb + 6 + half;
            int s0 = __shfl(s, i0), s1 = __shfl(s, i1);
            int s2 = __shfl(s, i2), s3 = __shfl(s, i3);
            float c0 = __shfl(p, i0), c1 = __shfl(p, i1);
            float c2 = __shfl(p, i2), c3 = __shfl(p, i3);
            if (i0 < deg) {
                f32x4 h = H4[(size_t)s0 * 32 + l32];
                a0.x = fmaf(c0, h.x, a0.x); a0.y = fmaf(c0, h.y, a0.y);
                a0.z = fmaf(c0, h.z, a0.z); a0.w = fmaf(c0, h.w, a0.w);
            }
            if (i1 < deg) {
                f32x4 h = H4[(size_t)s1 * 32 + l32];
                a1.x = fmaf(c1, h.x, a1.x); a1.y = fmaf(c1, h.y, a1.y);
                a1.z = fmaf(c1, h.z, a1.z); a1.w = fmaf(c1, h.w, a1.w);
            }
            if (i2 < deg) {
                f32x4 h = H4[(size_t)s2 * 32 + l32];
                a2.x = fmaf(c2, h.x, a2.x); a2.y = fmaf(c2, h.y, a2.y);
                a2.z = fmaf(c2, h.z, a2.z); a2.w = fmaf(c2, h.w, a2.w);
            }
            if (i3 < deg) {
                f32x4 h = H4[(size_t)s3 * 32 + l32];
                a3.x = fmaf(c3, h.x, a3.x); a3.y = fmaf(c3, h.y, a3.y);
                a3.z = fmaf(c3, h.z, a3.z); a3.w = fmaf(c3, h.w, a3.w);
            }
        }
    } else {
        float mym = -INFINITY;
        for (int i = beg + lane; i < end; i += 64)
            mym = fmaxf(mym, lrelu(AS[csr_src[i]] + ad));
#pragma unroll
        for (int off = 32; off; off >>= 1) mym = fmaxf(mym, __shfl_xor(mym, off));
        float m = fmaxf(mym, eself);
        float ssum = 0.f;
        for (int i = beg + lane; i < end; i += 64)
            ssum += expf(lrelu(AS[csr_src[i]] + ad) - m);
#pragma unroll
        for (int off = 32; off; off >>= 1) ssum += __shfl_xor(ssum, off);
        pself = expf(eself - m);
        ssum += pself;
        inv = 1.f / (ssum + 1e-16f);
        for (int i = beg; i < end; i += 2) {
            int idx = i + half;
            if (idx < end) {
                int s = csr_src[idx];
                float coef = expf(lrelu(AS[s] + ad) - m);
                f32x4 h = H4[(size_t)s * 32 + l32];
                a0.x = fmaf(coef, h.x, a0.x); a0.y = fmaf(coef, h.y, a0.y);
                a0.z = fmaf(coef, h.z, a0.z); a0.w = fmaf(coef, h.w, a0.w);
            }
        }
    }

    f32x4 acc;
    acc.x = a0.x + a1.x + a2.x + a3.x;
    acc.y = a0.y + a1.y + a2.y + a3.y;
    acc.z = a0.z + a1.z + a2.z + a3.z;
    acc.w = a0.w + a1.w + a2.w + a3.w;
    // combine half-waves
    acc.x += __shfl_xor(acc.x, 32);
    acc.y += __shfl_xor(acc.y, 32);
    acc.z += __shfl_xor(acc.z, 32);
    acc.w += __shfl_xor(acc.w, 32);

    if (half == 0) {
        f32x4 hs = H4[(size_t)node * 32 + l32];
        acc.x = fmaf(pself, hs.x, acc.x);
        acc.y = fmaf(pself, hs.y, acc.y);
        acc.z = fmaf(pself, hs.z, acc.z);
        acc.w = fmaf(pself, hs.w, acc.w);
        f32x4 b4 = ((const f32x4*)bias)[l32];
        f32x4 o;
        o.x = acc.x * inv + b4.x;
        o.y = acc.y * inv + b4.y;
        o.z = acc.z * inv + b4.z;
        o.w = acc.w * inv + b4.w;
        o.x = o.x > 0.f ? o.x : expm1f(o.x);
        o.y = o.y > 0.f ? o.y : expm1f(o.y);
        o.z = o.z > 0.f ? o.z : expm1f(o.z);
        o.w = o.w > 0.f ? o.w : expm1f(o.w);
        ((f32x4*)OUT)[(size_t)node * 32 + l32] = o;
    }
}

// ---------------- global mean pool: 2-phase ----------------
__global__ __launch_bounds__(128) void pool_partial(const float* __restrict__ F,
                                                    const int* __restrict__ start,
                                                    float* __restrict__ partial) {
    int b = blockIdx.x;
    int g = b >> 4, sub = b & 15;
    int c = threadIdx.x;
    int s0 = start[g], e0 = start[g + 1];
    float acc = 0.f;
    for (int i = s0 + sub; i < e0; i += 16) acc += F[(size_t)i * 128 + c];
    partial[(size_t)b * 128 + c] = acc;
}

__global__ __launch_bounds__(128) void pool_final(const float* __restrict__ partial,
                                                  const int* __restrict__ start,
                                                  float* __restrict__ out) {
    int g = blockIdx.x;
    int c = threadIdx.x;
    float v = 0.f;
#pragma unroll
    for (int u = 0; u < 16; ++u) v += partial[(size_t)(g * 16 + u) * 128 + c];
    int cnt = start[g + 1] - start[g];
    out[(size_t)g * 128 + c] = v / (float)(cnt > 1 ? cnt : 1);
}

extern "C" void kernel_launch(void* const* d_in, const int* in_sizes, int n_in,
                              void* d_out, int out_size, void* d_ws, size_t ws_size,
                              hipStream_t stream) {
    const float* x = (const float*)d_in[0];
    const int* edge_index = (const int*)d_in[1];
    const int* batch = (const int*)d_in[2];
    const float* W[3]   = {(const float*)d_in[3], (const float*)d_in[7], (const float*)d_in[11]};
    const float* avs[3] = {(const float*)d_in[4], (const float*)d_in[8], (const float*)d_in[12]};
    const float* avd[3] = {(const float*)d_in[5], (const float*)d_in[9], (const float*)d_in[13]};
    const float* bb[3]  = {(const float*)d_in[6], (const float*)d_in[10], (const float*)d_in[14]};
    int E0 = in_sizes[1] / 2;
    const int* esrc = edge_index;
    const int* edst = edge_index + E0;

    char* p = (char*)d_ws;
    auto alloc = [&](size_t bytes) -> void* {
        void* q = (void*)p;
        p += (bytes + 255) & ~(size_t)255;
        return q;
    };
    int* counts   = (int*)alloc((size_t)N_NODES * 4);
    int* offs     = (int*)alloc((size_t)(N_NODES + 1) * 4);
    int* cursor   = (int*)alloc((size_t)N_NODES * 4);
    int* csr_src  = (int*)alloc((size_t)E0 * 4);
    int* start    = (int*)alloc((N_GRAPHS + 1) * 4);
    int* bsum     = (int*)alloc(SCAN_B * 4);
    int* bpre     = (int*)alloc(SCAN_B * 4);
    float* AS     = (float*)alloc((size_t)N_NODES * 4);
    float* AD     = (float*)alloc((size_t)N_NODES * 4);
    float* Hbuf   = (float*)alloc((size_t)N_NODES * HID * 4);
    float* FA     = (float*)alloc((size_t)N_NODES * HID * 4);
    float* FB     = (float*)alloc((size_t)N_NODES * HID * 4);
    float* partial = (float*)alloc((size_t)N_GRAPHS * 16 * 128 * 4);
    _Float16* Wh[3], *Wl[3];
    for (int l = 0; l < 3; ++l) {
        Wh[l] = (_Float16*)alloc(16384 * 2);
        Wl[l] = (_Float16*)alloc(16384 * 2);
    }

    // CSR build
    hipMemsetAsync(counts, 0, (size_t)N_NODES * 4, stream);
    count_kernel<<<(E0 + 255) / 256, 256, 0, stream>>>(edst, E0, counts);
    block_reduce<<<SCAN_B, 256, 0, stream>>>(counts, bsum);
    scan_bsum<<<1, 256, 0, stream>>>(bsum, bpre, offs);
    block_scan<<<SCAN_B, 256, 0, stream>>>(counts, bpre, offs, cursor);
    scatter_kernel<<<(E0 + 255) / 256, 256, 0, stream>>>(esrc, edst, E0, cursor, csr_src);

    // graph boundaries
    init_start<<<1, 128, 0, stream>>>(start);
    find_start<<<(N_NODES + 255) / 256, 256, 0, stream>>>(batch, start);
    fix_start<<<1, 64, 0, stream>>>(start);

    // W fragment packing
    pack_w3<<<24, 256, 0, stream>>>(W[0], W[1], W[2], Wh[0], Wl[0], Wh[1], Wl[1], Wh[2], Wl[2]);

    // 3 GAT layers
    const float* cur = x;
    float* feat[2] = {FA, FB};
    for (int l = 0; l < 3; ++l) {
        gemm_mfma<<<(N_NODES + 63) / 64, 256, 0, stream>>>(cur, Wh[l], Wl[l], avs[l], avd[l],
                                                           Hbuf, AS, AD);
        float* nxt = feat[l & 1];
        aggregate_kernel<<<(N_NODES + 3) / 4, 256, 0, stream>>>(Hbuf, AS, AD, offs, csr_src,
                                                                bb[l], nxt);
        cur = nxt;
    }

    // global mean pool (2-phase)
    pool_partial<<<N_GRAPHS * 16, 128, 0, stream>>>(cur, start, partial);
    pool_final<<<N_GRAPHS, 128, 0, stream>>>(partial, start, (float*)d_out);
}